// Round 1
// baseline (1317.495 us; speedup 1.0000x reference)
//
#include <hip/hip_runtime.h>
#include <math.h>

#define N_NODES 200000
#define N_EDGES 6400000
#define N_GRAPHS 128

// ---------------- edge kernels ----------------

__global__ void k_deg(const int* __restrict__ dst, float* __restrict__ deg) {
    const int4* d4 = (const int4*)dst;
    const int n4 = N_EDGES / 4;
    for (int e = blockIdx.x * blockDim.x + threadIdx.x; e < n4; e += gridDim.x * blockDim.x) {
        int4 d = d4[e];
        atomicAdd(&deg[d.x], 1.0f);
        atomicAdd(&deg[d.y], 1.0f);
        atomicAdd(&deg[d.z], 1.0f);
        atomicAdd(&deg[d.w], 1.0f);
    }
}

// dinv = rsqrt(deg + 1 self-loop); xd = x * dinv (single gather value for pass1)
__global__ void k_dinv(const float* __restrict__ x, float* __restrict__ deg_dinv,
                       float* __restrict__ xd) {
    int i = blockIdx.x * blockDim.x + threadIdx.x;
    if (i < N_NODES) {
        float dinv = rsqrtf(deg_dinv[i] + 1.0f);
        deg_dinv[i] = dinv;
        xd[i] = x[i] * dinv;
    }
}

// t[dst] += x[src]*dinv[src]
__global__ void k_pass1(const int* __restrict__ src, const int* __restrict__ dst,
                        const float* __restrict__ xd, float* __restrict__ t) {
    const int4* s4 = (const int4*)src;
    const int4* d4 = (const int4*)dst;
    const int n4 = N_EDGES / 4;
    for (int e = blockIdx.x * blockDim.x + threadIdx.x; e < n4; e += gridDim.x * blockDim.x) {
        int4 s = s4[e];
        int4 d = d4[e];
        atomicAdd(&t[d.x], xd[s.x]);
        atomicAdd(&t[d.y], xd[s.y]);
        atomicAdd(&t[d.z], xd[s.z]);
        atomicAdd(&t[d.w], xd[s.w]);
    }
}

// agg1 = dinv*(t + xd)   (self-loop folded in); pair = {agg1*dinv, dinv} for pass2 gather
__global__ void k_agg1(const float* __restrict__ dinv, const float* __restrict__ xd,
                       float* __restrict__ t, float2* __restrict__ pair) {
    int i = blockIdx.x * blockDim.x + threadIdx.x;
    if (i < N_NODES) {
        float di = dinv[i];
        float a = di * (t[i] + xd[i]);
        t[i] = a;  // keep agg1 for self-loop term in node2
        pair[i] = make_float2(a * di, di);
    }
}

// s1[dst] += agg1[src]*dinv[src];  s0[dst] += dinv[src]
__global__ void k_pass2(const int* __restrict__ src, const int* __restrict__ dst,
                        const float2* __restrict__ pair,
                        float* __restrict__ s1, float* __restrict__ s0) {
    const int4* s4 = (const int4*)src;
    const int4* d4 = (const int4*)dst;
    const int n4 = N_EDGES / 4;
    for (int e = blockIdx.x * blockDim.x + threadIdx.x; e < n4; e += gridDim.x * blockDim.x) {
        int4 s = s4[e];
        int4 d = d4[e];
        float2 p0 = pair[s.x];
        float2 p1 = pair[s.y];
        float2 p2 = pair[s.z];
        float2 p3 = pair[s.w];
        atomicAdd(&s1[d.x], p0.x); atomicAdd(&s0[d.x], p0.y);
        atomicAdd(&s1[d.y], p1.x); atomicAdd(&s0[d.y], p1.y);
        atomicAdd(&s1[d.z], p2.x); atomicAdd(&s0[d.z], p2.y);
        atomicAdd(&s1[d.w], p3.x); atomicAdd(&s0[d.w], p3.y);
    }
}

// finalize per-node s1f,s0f and accumulate per-graph (wave-aggregated; batch is sorted)
__global__ void k_node2(const float* __restrict__ dinv, const float* __restrict__ agg1,
                        const float* __restrict__ s1, const float* __restrict__ s0,
                        const int* __restrict__ batch, float* __restrict__ gacc) {
    int i = blockIdx.x * blockDim.x + threadIdx.x;
    float s1f = 0.0f, s0f = 0.0f;
    int g = 0;
    bool valid = (i < N_NODES);
    if (valid) {
        float di = dinv[i];
        s1f = di * (s1[i] + agg1[i] * di);
        s0f = di * (s0[i] + di);
        g = batch[i];
    }
    int g0 = __shfl(g, 0);
    bool uni = __all(valid && (g == g0));
    if (uni) {
        for (int off = 32; off; off >>= 1) {
            s1f += __shfl_down(s1f, off);
            s0f += __shfl_down(s0f, off);
        }
        if ((threadIdx.x & 63) == 0) {
            atomicAdd(&gacc[g0], s1f);
            atomicAdd(&gacc[N_GRAPHS + g0], s0f);
            atomicAdd(&gacc[2 * N_GRAPHS + g0], 64.0f);
        }
    } else if (valid) {
        atomicAdd(&gacc[g], s1f);
        atomicAdd(&gacc[N_GRAPHS + g], s0f);
        atomicAdd(&gacc[2 * N_GRAPHS + g], 1.0f);
    }
}

// pooled = (u*GS1 + v*GS0 + cnt*b2)/max(cnt,1); log_softmax over 8 classes
__global__ void k_final(const float* __restrict__ gacc,
                        const float* __restrict__ W1, const float* __restrict__ b1,
                        const float* __restrict__ W2, const float* __restrict__ b2,
                        float* __restrict__ out) {
    int g = threadIdx.x;
    if (g >= N_GRAPHS) return;
    float GS1 = gacc[g];
    float GS0 = gacc[N_GRAPHS + g];
    float cnt = gacc[2 * N_GRAPHS + g];
    float denom = fmaxf(cnt, 1.0f);
    float p[8];
    for (int k = 0; k < 8; ++k) {
        float u = 0.0f, v = 0.0f;
        for (int c = 0; c < 32; ++c) {
            u += W1[c] * W2[c * 8 + k];
            v += b1[c] * W2[c * 8 + k];
        }
        p[k] = (u * GS1 + v * GS0 + cnt * b2[k]) / denom;
    }
    float m = p[0];
    for (int k = 1; k < 8; ++k) m = fmaxf(m, p[k]);
    float s = 0.0f;
    for (int k = 0; k < 8; ++k) s += expf(p[k] - m);
    float l = logf(s);
    for (int k = 0; k < 8; ++k) out[g * 8 + k] = p[k] - m - l;
}

// ---------------- launch ----------------

extern "C" void kernel_launch(void* const* d_in, const int* in_sizes, int n_in,
                              void* d_out, int out_size, void* d_ws, size_t ws_size,
                              hipStream_t stream) {
    const float* x     = (const float*)d_in[0];
    const int*   edge  = (const int*)d_in[1];   // int64 in reference; harness delivers int32
    const int*   batch = (const int*)d_in[2];
    const float* W1    = (const float*)d_in[3];
    const float* b1    = (const float*)d_in[4];
    const float* W2    = (const float*)d_in[5];
    const float* b2    = (const float*)d_in[6];
    float* out = (float*)d_out;

    const int* src = edge;
    const int* dst = edge + N_EDGES;

    float* ws   = (float*)d_ws;
    float* dinv = ws;                 // [N]  deg accum -> dinv
    float* t    = ws + 1 * N_NODES;   // [N]  pass1 accum -> agg1
    float* s1   = ws + 2 * N_NODES;   // [N]
    float* s0   = ws + 3 * N_NODES;   // [N]
    float* xd   = ws + 4 * N_NODES;   // [N]
    float2* pair = (float2*)(ws + 5 * N_NODES);  // [N] float2 (8B-aligned: 5N*4 % 8 == 0)
    float* gacc = ws + 7 * N_NODES;   // [3*128]

    // zero the accumulators (deg, t, s1, s0) and graph bins
    hipMemsetAsync(ws, 0, (size_t)4 * N_NODES * sizeof(float), stream);
    hipMemsetAsync(gacc, 0, (size_t)3 * N_GRAPHS * sizeof(float), stream);

    const int EB = 2048, ET = 256;                     // edge-pass grid (grid-stride)
    const int NB = (N_NODES + 255) / 256, NT = 256;    // node-pass grid

    k_deg<<<EB, ET, 0, stream>>>(dst, dinv);
    k_dinv<<<NB, NT, 0, stream>>>(x, dinv, xd);
    k_pass1<<<EB, ET, 0, stream>>>(src, dst, xd, t);
    k_agg1<<<NB, NT, 0, stream>>>(dinv, xd, t, pair);
    k_pass2<<<EB, ET, 0, stream>>>(src, dst, pair, s1, s0);
    k_node2<<<NB, NT, 0, stream>>>(dinv, t, s1, s0, batch, gacc);
    k_final<<<1, 128, 0, stream>>>(gacc, W1, b1, W2, b2, out);
}

// Round 2
// 255.635 us; speedup vs baseline: 5.1538x; 5.1538x over previous
//
#include <hip/hip_runtime.h>
#include <math.h>

#define N_NODES 200000
#define N_EDGES 6400000
#define N_GRAPHS 128

// ---- binned (counting-sort) path parameters ----
#define NBK   782          // buckets of 256 nodes: 782*256 = 200192 >= 200000
#define EBLK  256          // phase-A blocks
#define EPB   (N_EDGES / EBLK)   // 25000 edges per phase-A block

// ============================================================
// Fast path: counting-sort by dst bucket + LDS aggregation
// ============================================================

// Phase A0: per-block histogram of dst buckets
__global__ void kA0_hist(const int* __restrict__ dst, unsigned* __restrict__ countMat) {
    __shared__ unsigned cnt[NBK];
    for (int t = threadIdx.x; t < NBK; t += blockDim.x) cnt[t] = 0;
    __syncthreads();
    const int4* d4 = (const int4*)(dst + blockIdx.x * EPB);
    for (int e = threadIdx.x; e < EPB / 4; e += blockDim.x) {
        int4 d = d4[e];
        atomicAdd(&cnt[d.x >> 8], 1u);
        atomicAdd(&cnt[d.y >> 8], 1u);
        atomicAdd(&cnt[d.z >> 8], 1u);
        atomicAdd(&cnt[d.w >> 8], 1u);
    }
    __syncthreads();
    for (int t = threadIdx.x; t < NBK; t += blockDim.x)
        countMat[blockIdx.x * NBK + t] = cnt[t];
}

// Phase A-scan1: per bucket, exclusive scan over the 256 block counts (in place),
// column sum -> colsum. One wave per bucket.
__global__ void kScanBlk(unsigned* __restrict__ mat, unsigned* __restrict__ colsum) {
    int bkt = blockIdx.x * 4 + (threadIdx.x >> 6);
    if (bkt >= NBK) return;
    int lane = threadIdx.x & 63;
    unsigned carry = 0;
    for (int k = 0; k < 4; ++k) {
        int blk = k * 64 + lane;
        unsigned v = mat[blk * NBK + bkt];
        unsigned s = v;
        for (int off = 1; off < 64; off <<= 1) {
            unsigned u = __shfl_up(s, off);
            if (lane >= off) s += u;
        }
        mat[blk * NBK + bkt] = carry + s - v;   // exclusive within column
        carry += __shfl(s, 63);
    }
    colsum[bkt] = carry;
}

// Phase A-scan2: exclusive scan over buckets -> bucketBase[NBK+1]
__global__ void kScanBkt(const unsigned* __restrict__ colsum, unsigned* __restrict__ bucketBase) {
    __shared__ unsigned wsum[16];
    int t = threadIdx.x;
    int lane = t & 63, w = t >> 6;
    unsigned v = (t < NBK) ? colsum[t] : 0u;
    unsigned s = v;
    for (int off = 1; off < 64; off <<= 1) {
        unsigned u = __shfl_up(s, off);
        if (lane >= off) s += u;
    }
    if (lane == 63) wsum[w] = s;
    __syncthreads();
    if (w == 0 && lane < 16) {
        int nw = blockDim.x >> 6;
        unsigned ws = (lane < nw) ? wsum[lane] : 0u;
        unsigned ss = ws;
        for (int off = 1; off < 16; off <<= 1) {
            unsigned u = __shfl_up(ss, off);
            if (lane >= off) ss += u;
        }
        wsum[lane] = ss - ws;  // exclusive wave prefix
    }
    __syncthreads();
    unsigned excl = s - v + wsum[w];
    if (t < NBK) bucketBase[t] = excl;
    if (t == NBK - 1) bucketBase[NBK] = excl + v;
}

// Phase A1: scatter packed edges (src<<8 | dst&255) into bucket-ordered array
__global__ void kA1_scatter(const int* __restrict__ src, const int* __restrict__ dst,
                            const unsigned* __restrict__ baseMat,
                            const unsigned* __restrict__ bucketBase,
                            unsigned* __restrict__ binned) {
    __shared__ unsigned cur[NBK];
    for (int t = threadIdx.x; t < NBK; t += blockDim.x)
        cur[t] = baseMat[blockIdx.x * NBK + t] + bucketBase[t];
    __syncthreads();
    const int base_e = blockIdx.x * EPB;
    const int4* s4 = (const int4*)(src + base_e);
    const int4* d4 = (const int4*)(dst + base_e);
    for (int e = threadIdx.x; e < EPB / 4; e += blockDim.x) {
        int4 s = s4[e];
        int4 d = d4[e];
        unsigned p;
        p = atomicAdd(&cur[d.x >> 8], 1u); binned[p] = ((unsigned)s.x << 8) | (unsigned)(d.x & 255);
        p = atomicAdd(&cur[d.y >> 8], 1u); binned[p] = ((unsigned)s.y << 8) | (unsigned)(d.y & 255);
        p = atomicAdd(&cur[d.z >> 8], 1u); binned[p] = ((unsigned)s.z << 8) | (unsigned)(d.z & 255);
        p = atomicAdd(&cur[d.w >> 8], 1u); binned[p] = ((unsigned)s.w << 8) | (unsigned)(d.w & 255);
    }
}

// Phase B: deg (LDS histogram per bucket) -> dinv, xd
__global__ void kB_deg(const unsigned* __restrict__ binned, const unsigned* __restrict__ bucketBase,
                       const float* __restrict__ x, float* __restrict__ dinv,
                       float* __restrict__ xd) {
    __shared__ unsigned deg[256];
    deg[threadIdx.x] = 0;
    __syncthreads();
    int b = blockIdx.x;
    unsigned lo = bucketBase[b], hi = bucketBase[b + 1];
    for (unsigned e = lo + threadIdx.x; e < hi; e += blockDim.x)
        atomicAdd(&deg[binned[e] & 255u], 1u);
    __syncthreads();
    int node = b * 256 + threadIdx.x;
    if (node < N_NODES) {
        float di = rsqrtf((float)deg[threadIdx.x] + 1.0f);
        dinv[node] = di;
        xd[node] = x[node] * di;
    }
}

// Phase C: t[dst] += xd[src] (LDS), then pair = {agg1*dinv, dinv}
__global__ void kC_pass1(const unsigned* __restrict__ binned, const unsigned* __restrict__ bucketBase,
                         const float* __restrict__ xd, const float* __restrict__ dinv,
                         float2* __restrict__ pair) {
    __shared__ float tacc[256];
    tacc[threadIdx.x] = 0.0f;
    __syncthreads();
    int b = blockIdx.x;
    unsigned lo = bucketBase[b], hi = bucketBase[b + 1];
    for (unsigned e = lo + threadIdx.x; e < hi; e += blockDim.x) {
        unsigned en = binned[e];
        atomicAdd(&tacc[en & 255u], xd[en >> 8]);
    }
    __syncthreads();
    int node = b * 256 + threadIdx.x;
    if (node < N_NODES) {
        float di = dinv[node];
        float a = di * (tacc[threadIdx.x] + xd[node]);   // agg1 (self-loop folded)
        pair[node] = make_float2(a * di, di);
    }
}

// Phase D: s1[dst] += pair[src].x, s0[dst] += pair[src].y (LDS), finalize + per-graph pool
__global__ void kD_pass2(const unsigned* __restrict__ binned, const unsigned* __restrict__ bucketBase,
                         const float2* __restrict__ pair, const int* __restrict__ batch,
                         float* __restrict__ gacc) {
    __shared__ float s1a[256], s0a[256];
    s1a[threadIdx.x] = 0.0f;
    s0a[threadIdx.x] = 0.0f;
    __syncthreads();
    int b = blockIdx.x;
    unsigned lo = bucketBase[b], hi = bucketBase[b + 1];
    for (unsigned e = lo + threadIdx.x; e < hi; e += blockDim.x) {
        unsigned en = binned[e];
        float2 p = pair[en >> 8];
        unsigned ld = en & 255u;
        atomicAdd(&s1a[ld], p.x);
        atomicAdd(&s0a[ld], p.y);
    }
    __syncthreads();
    int node = b * 256 + threadIdx.x;
    float s1f = 0.0f, s0f = 0.0f;
    int g = 0;
    bool valid = (node < N_NODES);
    if (valid) {
        float2 pr = pair[node];          // {agg1*di, di}
        float di = pr.y;
        s1f = di * (s1a[threadIdx.x] + pr.x);   // self-loop: + agg1*di
        s0f = di * (s0a[threadIdx.x] + di);     // self-loop: + di
        g = batch[node];
    }
    int g0 = __shfl(g, 0);
    bool uni = __all(valid && (g == g0));
    if (uni) {
        for (int off = 32; off; off >>= 1) {
            s1f += __shfl_down(s1f, off);
            s0f += __shfl_down(s0f, off);
        }
        if ((threadIdx.x & 63) == 0) {
            atomicAdd(&gacc[g0], s1f);
            atomicAdd(&gacc[N_GRAPHS + g0], s0f);
            atomicAdd(&gacc[2 * N_GRAPHS + g0], 64.0f);
        }
    } else if (valid) {
        atomicAdd(&gacc[g], s1f);
        atomicAdd(&gacc[N_GRAPHS + g], s0f);
        atomicAdd(&gacc[2 * N_GRAPHS + g], 1.0f);
    }
}

// Final: pooled = (u*GS1 + v*GS0 + cnt*b2)/max(cnt,1); log_softmax over 8 classes
__global__ void k_final(const float* __restrict__ gacc,
                        const float* __restrict__ W1, const float* __restrict__ b1,
                        const float* __restrict__ W2, const float* __restrict__ b2,
                        float* __restrict__ out) {
    int g = threadIdx.x;
    if (g >= N_GRAPHS) return;
    float GS1 = gacc[g];
    float GS0 = gacc[N_GRAPHS + g];
    float cnt = gacc[2 * N_GRAPHS + g];
    float denom = fmaxf(cnt, 1.0f);
    float p[8];
    for (int k = 0; k < 8; ++k) {
        float u = 0.0f, v = 0.0f;
        for (int c = 0; c < 32; ++c) {
            u += W1[c] * W2[c * 8 + k];
            v += b1[c] * W2[c * 8 + k];
        }
        p[k] = (u * GS1 + v * GS0 + cnt * b2[k]) / denom;
    }
    float m = p[0];
    for (int k = 1; k < 8; ++k) m = fmaxf(m, p[k]);
    float s = 0.0f;
    for (int k = 0; k < 8; ++k) s += expf(p[k] - m);
    float l = logf(s);
    for (int k = 0; k < 8; ++k) out[g * 8 + k] = p[k] - m - l;
}

// ============================================================
// Fallback path (R1): global-atomic pipeline (used if ws too small)
// ============================================================

__global__ void k_deg(const int* __restrict__ dst, float* __restrict__ deg) {
    const int4* d4 = (const int4*)dst;
    const int n4 = N_EDGES / 4;
    for (int e = blockIdx.x * blockDim.x + threadIdx.x; e < n4; e += gridDim.x * blockDim.x) {
        int4 d = d4[e];
        atomicAdd(&deg[d.x], 1.0f);
        atomicAdd(&deg[d.y], 1.0f);
        atomicAdd(&deg[d.z], 1.0f);
        atomicAdd(&deg[d.w], 1.0f);
    }
}

__global__ void k_dinv(const float* __restrict__ x, float* __restrict__ deg_dinv,
                       float* __restrict__ xd) {
    int i = blockIdx.x * blockDim.x + threadIdx.x;
    if (i < N_NODES) {
        float dinv = rsqrtf(deg_dinv[i] + 1.0f);
        deg_dinv[i] = dinv;
        xd[i] = x[i] * dinv;
    }
}

__global__ void k_pass1(const int* __restrict__ src, const int* __restrict__ dst,
                        const float* __restrict__ xd, float* __restrict__ t) {
    const int4* s4 = (const int4*)src;
    const int4* d4 = (const int4*)dst;
    const int n4 = N_EDGES / 4;
    for (int e = blockIdx.x * blockDim.x + threadIdx.x; e < n4; e += gridDim.x * blockDim.x) {
        int4 s = s4[e];
        int4 d = d4[e];
        atomicAdd(&t[d.x], xd[s.x]);
        atomicAdd(&t[d.y], xd[s.y]);
        atomicAdd(&t[d.z], xd[s.z]);
        atomicAdd(&t[d.w], xd[s.w]);
    }
}

__global__ void k_agg1(const float* __restrict__ dinv, const float* __restrict__ xd,
                       float* __restrict__ t, float2* __restrict__ pair) {
    int i = blockIdx.x * blockDim.x + threadIdx.x;
    if (i < N_NODES) {
        float di = dinv[i];
        float a = di * (t[i] + xd[i]);
        t[i] = a;
        pair[i] = make_float2(a * di, di);
    }
}

__global__ void k_pass2(const int* __restrict__ src, const int* __restrict__ dst,
                        const float2* __restrict__ pair,
                        float* __restrict__ s1, float* __restrict__ s0) {
    const int4* s4 = (const int4*)src;
    const int4* d4 = (const int4*)dst;
    const int n4 = N_EDGES / 4;
    for (int e = blockIdx.x * blockDim.x + threadIdx.x; e < n4; e += gridDim.x * blockDim.x) {
        int4 s = s4[e];
        int4 d = d4[e];
        float2 p0 = pair[s.x];
        float2 p1 = pair[s.y];
        float2 p2 = pair[s.z];
        float2 p3 = pair[s.w];
        atomicAdd(&s1[d.x], p0.x); atomicAdd(&s0[d.x], p0.y);
        atomicAdd(&s1[d.y], p1.x); atomicAdd(&s0[d.y], p1.y);
        atomicAdd(&s1[d.z], p2.x); atomicAdd(&s0[d.z], p2.y);
        atomicAdd(&s1[d.w], p3.x); atomicAdd(&s0[d.w], p3.y);
    }
}

__global__ void k_node2(const float* __restrict__ dinv, const float* __restrict__ agg1,
                        const float* __restrict__ s1, const float* __restrict__ s0,
                        const int* __restrict__ batch, float* __restrict__ gacc) {
    int i = blockIdx.x * blockDim.x + threadIdx.x;
    float s1f = 0.0f, s0f = 0.0f;
    int g = 0;
    bool valid = (i < N_NODES);
    if (valid) {
        float di = dinv[i];
        s1f = di * (s1[i] + agg1[i] * di);
        s0f = di * (s0[i] + di);
        g = batch[i];
    }
    int g0 = __shfl(g, 0);
    bool uni = __all(valid && (g == g0));
    if (uni) {
        for (int off = 32; off; off >>= 1) {
            s1f += __shfl_down(s1f, off);
            s0f += __shfl_down(s0f, off);
        }
        if ((threadIdx.x & 63) == 0) {
            atomicAdd(&gacc[g0], s1f);
            atomicAdd(&gacc[N_GRAPHS + g0], s0f);
            atomicAdd(&gacc[2 * N_GRAPHS + g0], 64.0f);
        }
    } else if (valid) {
        atomicAdd(&gacc[g], s1f);
        atomicAdd(&gacc[N_GRAPHS + g], s0f);
        atomicAdd(&gacc[2 * N_GRAPHS + g], 1.0f);
    }
}

// ---------------- launch ----------------

extern "C" void kernel_launch(void* const* d_in, const int* in_sizes, int n_in,
                              void* d_out, int out_size, void* d_ws, size_t ws_size,
                              hipStream_t stream) {
    const float* x     = (const float*)d_in[0];
    const int*   edge  = (const int*)d_in[1];   // int64 in ref; harness delivers int32
    const int*   batch = (const int*)d_in[2];
    const float* W1    = (const float*)d_in[3];
    const float* b1    = (const float*)d_in[4];
    const float* W2    = (const float*)d_in[5];
    const float* b2    = (const float*)d_in[6];
    float* out = (float*)d_out;

    const int* src = edge;
    const int* dst = edge + N_EDGES;

    // ---- workspace layout (u32/float units) ----
    // fast path:
    //   binned    [6,400,000]
    //   countMat  [EBLK*NBK = 200,192]
    //   colsum    [782]
    //   bucketBase[783]
    //   dinv      [200,000]
    //   xd        [200,000]
    //   pair      [200,000 float2]  (8B aligned)
    //   gacc      [384]
    const size_t o_binned = 0;
    const size_t o_cmat   = o_binned + (size_t)N_EDGES;
    const size_t o_colsum = o_cmat + (size_t)EBLK * NBK;
    const size_t o_bbase  = o_colsum + NBK;
    const size_t o_dinv   = o_bbase + NBK + 1;
    const size_t o_xd     = o_dinv + N_NODES;
    size_t o_pair         = o_xd + N_NODES;
    if (o_pair & 1) o_pair++;                    // 8B align for float2
    const size_t o_gacc   = o_pair + 2 * (size_t)N_NODES;
    const size_t need_u32 = o_gacc + 3 * N_GRAPHS;

    unsigned* ws_u = (unsigned*)d_ws;
    float*    ws_f = (float*)d_ws;

    if (ws_size >= need_u32 * 4) {
        // ---------- fast path ----------
        unsigned* binned     = ws_u + o_binned;
        unsigned* countMat   = ws_u + o_cmat;
        unsigned* colsum     = ws_u + o_colsum;
        unsigned* bucketBase = ws_u + o_bbase;
        float*    dinv       = ws_f + o_dinv;
        float*    xd         = ws_f + o_xd;
        float2*   pair       = (float2*)(ws_f + o_pair);
        float*    gacc       = ws_f + o_gacc;

        hipMemsetAsync(gacc, 0, 3 * N_GRAPHS * sizeof(float), stream);

        kA0_hist   <<<EBLK, 256, 0, stream>>>(dst, countMat);
        kScanBlk   <<<(NBK + 3) / 4, 256, 0, stream>>>(countMat, colsum);
        kScanBkt   <<<1, 832, 0, stream>>>(colsum, bucketBase);
        kA1_scatter<<<EBLK, 256, 0, stream>>>(src, dst, countMat, bucketBase, binned);
        kB_deg     <<<NBK, 256, 0, stream>>>(binned, bucketBase, x, dinv, xd);
        kC_pass1   <<<NBK, 256, 0, stream>>>(binned, bucketBase, xd, dinv, pair);
        kD_pass2   <<<NBK, 256, 0, stream>>>(binned, bucketBase, pair, batch, gacc);
        k_final    <<<1, 128, 0, stream>>>(gacc, W1, b1, W2, b2, out);
    } else {
        // ---------- fallback: global-atomic path ----------
        float* dinv = ws_f;
        float* t    = ws_f + 1 * N_NODES;
        float* s1   = ws_f + 2 * N_NODES;
        float* s0   = ws_f + 3 * N_NODES;
        float* xd   = ws_f + 4 * N_NODES;
        float2* pair = (float2*)(ws_f + 5 * N_NODES);
        float* gacc = ws_f + 7 * N_NODES;

        hipMemsetAsync(ws_f, 0, (size_t)4 * N_NODES * sizeof(float), stream);
        hipMemsetAsync(gacc, 0, (size_t)3 * N_GRAPHS * sizeof(float), stream);

        const int EB = 2048, ET = 256;
        const int NB = (N_NODES + 255) / 256, NT = 256;

        k_deg  <<<EB, ET, 0, stream>>>(dst, dinv);
        k_dinv <<<NB, NT, 0, stream>>>(x, dinv, xd);
        k_pass1<<<EB, ET, 0, stream>>>(src, dst, xd, t);
        k_agg1 <<<NB, NT, 0, stream>>>(dinv, xd, t, pair);
        k_pass2<<<EB, ET, 0, stream>>>(src, dst, pair, s1, s0);
        k_node2<<<NB, NT, 0, stream>>>(dinv, t, s1, s0, batch, gacc);
        k_final<<<1, 128, 0, stream>>>(gacc, W1, b1, W2, b2, out);
    }
}

// Round 3
// 229.621 us; speedup vs baseline: 5.7377x; 1.1133x over previous
//
#include <hip/hip_runtime.h>
#include <math.h>

#define N_NODES 200000
#define N_EDGES 6400000
#define N_GRAPHS 128

// ---- binned (counting-sort) path parameters ----
#define NBK   782          // buckets of 256 nodes: 782*256 = 200192 >= 200000
#define EBLK  256          // phase-A blocks
#define EPB   (N_EDGES / EBLK)   // 25000 edges per phase-A block

// ============================================================
// Fast path: counting-sort by dst bucket + LDS aggregation
// ============================================================

// Phase A0: per-block histogram of dst buckets
__global__ void kA0_hist(const int* __restrict__ dst, unsigned* __restrict__ countMat) {
    __shared__ unsigned cnt[NBK];
    for (int t = threadIdx.x; t < NBK; t += blockDim.x) cnt[t] = 0;
    __syncthreads();
    const int4* d4 = (const int4*)(dst + blockIdx.x * EPB);
    for (int e = threadIdx.x; e < EPB / 4; e += blockDim.x) {
        int4 d = d4[e];
        atomicAdd(&cnt[d.x >> 8], 1u);
        atomicAdd(&cnt[d.y >> 8], 1u);
        atomicAdd(&cnt[d.z >> 8], 1u);
        atomicAdd(&cnt[d.w >> 8], 1u);
    }
    __syncthreads();
    for (int t = threadIdx.x; t < NBK; t += blockDim.x)
        countMat[blockIdx.x * NBK + t] = cnt[t];
}

// Phase A-scan1: per bucket, exclusive scan over the 256 block counts (in place),
// column sum -> colsum. One wave per bucket.
__global__ void kScanBlk(unsigned* __restrict__ mat, unsigned* __restrict__ colsum) {
    int bkt = blockIdx.x * 4 + (threadIdx.x >> 6);
    if (bkt >= NBK) return;
    int lane = threadIdx.x & 63;
    unsigned carry = 0;
    for (int k = 0; k < 4; ++k) {
        int blk = k * 64 + lane;
        unsigned v = mat[blk * NBK + bkt];
        unsigned s = v;
        for (int off = 1; off < 64; off <<= 1) {
            unsigned u = __shfl_up(s, off);
            if (lane >= off) s += u;
        }
        mat[blk * NBK + bkt] = carry + s - v;   // exclusive within column
        carry += __shfl(s, 63);
    }
    colsum[bkt] = carry;
}

// Phase A-scan2: exclusive scan over buckets -> bucketBase[NBK+1]
__global__ void kScanBkt(const unsigned* __restrict__ colsum, unsigned* __restrict__ bucketBase) {
    __shared__ unsigned wsum[16];
    int t = threadIdx.x;
    int lane = t & 63, w = t >> 6;
    unsigned v = (t < NBK) ? colsum[t] : 0u;
    unsigned s = v;
    for (int off = 1; off < 64; off <<= 1) {
        unsigned u = __shfl_up(s, off);
        if (lane >= off) s += u;
    }
    if (lane == 63) wsum[w] = s;
    __syncthreads();
    if (w == 0 && lane < 16) {
        int nw = blockDim.x >> 6;
        unsigned ws = (lane < nw) ? wsum[lane] : 0u;
        unsigned ss = ws;
        for (int off = 1; off < 16; off <<= 1) {
            unsigned u = __shfl_up(ss, off);
            if (lane >= off) ss += u;
        }
        wsum[lane] = ss - ws;  // exclusive wave prefix
    }
    __syncthreads();
    unsigned excl = s - v + wsum[w];
    if (t < NBK) bucketBase[t] = excl;
    if (t == NBK - 1) bucketBase[NBK] = excl + v;
}

// Phase A1: scatter packed edges (src<<8 | dst&255) into bucket-ordered array
__global__ void kA1_scatter(const int* __restrict__ src, const int* __restrict__ dst,
                            const unsigned* __restrict__ baseMat,
                            const unsigned* __restrict__ bucketBase,
                            unsigned* __restrict__ binned) {
    __shared__ unsigned cur[NBK];
    for (int t = threadIdx.x; t < NBK; t += blockDim.x)
        cur[t] = baseMat[blockIdx.x * NBK + t] + bucketBase[t];
    __syncthreads();
    const int base_e = blockIdx.x * EPB;
    const int4* s4 = (const int4*)(src + base_e);
    const int4* d4 = (const int4*)(dst + base_e);
    for (int e = threadIdx.x; e < EPB / 4; e += blockDim.x) {
        int4 s = s4[e];
        int4 d = d4[e];
        unsigned p;
        p = atomicAdd(&cur[d.x >> 8], 1u); binned[p] = ((unsigned)s.x << 8) | (unsigned)(d.x & 255);
        p = atomicAdd(&cur[d.y >> 8], 1u); binned[p] = ((unsigned)s.y << 8) | (unsigned)(d.y & 255);
        p = atomicAdd(&cur[d.z >> 8], 1u); binned[p] = ((unsigned)s.z << 8) | (unsigned)(d.z & 255);
        p = atomicAdd(&cur[d.w >> 8], 1u); binned[p] = ((unsigned)s.w << 8) | (unsigned)(d.w & 255);
    }
}

// Phase B: deg (LDS histogram per bucket) -> dinv, xd.  4-edge ILP per thread.
__global__ void __launch_bounds__(512)
kB_deg(const unsigned* __restrict__ binned, const unsigned* __restrict__ bucketBase,
       const float* __restrict__ x, float* __restrict__ dinv, float* __restrict__ xd) {
    __shared__ unsigned deg[256];
    if (threadIdx.x < 256) deg[threadIdx.x] = 0;
    __syncthreads();
    int b = blockIdx.x;
    unsigned lo = bucketBase[b], hi = bucketBase[b + 1];
    const uint4* b4 = (const uint4*)binned;
    for (unsigned q = lo / 4 + threadIdx.x; q * 4 < hi; q += blockDim.x) {
        uint4 v = b4[q];
        unsigned e0 = q * 4;
        if (e0 >= lo && e0 + 3 < hi) {
            atomicAdd(&deg[v.x & 255u], 1u);
            atomicAdd(&deg[v.y & 255u], 1u);
            atomicAdd(&deg[v.z & 255u], 1u);
            atomicAdd(&deg[v.w & 255u], 1u);
        } else {
            if (e0     >= lo && e0     < hi) atomicAdd(&deg[v.x & 255u], 1u);
            if (e0 + 1 >= lo && e0 + 1 < hi) atomicAdd(&deg[v.y & 255u], 1u);
            if (e0 + 2 >= lo && e0 + 2 < hi) atomicAdd(&deg[v.z & 255u], 1u);
            if (e0 + 3 >= lo && e0 + 3 < hi) atomicAdd(&deg[v.w & 255u], 1u);
        }
    }
    __syncthreads();
    if (threadIdx.x < 256) {
        int node = b * 256 + threadIdx.x;
        if (node < N_NODES) {
            float di = rsqrtf((float)deg[threadIdx.x] + 1.0f);
            dinv[node] = di;
            xd[node] = x[node] * di;
        }
    }
}

// Phase C: t[dst] += xd[src] (LDS), then pair = {agg1*dinv, dinv}.  4-edge ILP.
__global__ void __launch_bounds__(512)
kC_pass1(const unsigned* __restrict__ binned, const unsigned* __restrict__ bucketBase,
         const float* __restrict__ xd, const float* __restrict__ dinv,
         float2* __restrict__ pair) {
    __shared__ float tacc[256];
    if (threadIdx.x < 256) tacc[threadIdx.x] = 0.0f;
    __syncthreads();
    int b = blockIdx.x;
    unsigned lo = bucketBase[b], hi = bucketBase[b + 1];
    const uint4* b4 = (const uint4*)binned;
    for (unsigned q = lo / 4 + threadIdx.x; q * 4 < hi; q += blockDim.x) {
        uint4 v = b4[q];
        unsigned e0 = q * 4;
        // issue all gathers unconditionally (src indices always valid nodes)
        float g0 = xd[v.x >> 8];
        float g1 = xd[v.y >> 8];
        float g2 = xd[v.z >> 8];
        float g3 = xd[v.w >> 8];
        if (e0 >= lo && e0 + 3 < hi) {
            atomicAdd(&tacc[v.x & 255u], g0);
            atomicAdd(&tacc[v.y & 255u], g1);
            atomicAdd(&tacc[v.z & 255u], g2);
            atomicAdd(&tacc[v.w & 255u], g3);
        } else {
            if (e0     >= lo && e0     < hi) atomicAdd(&tacc[v.x & 255u], g0);
            if (e0 + 1 >= lo && e0 + 1 < hi) atomicAdd(&tacc[v.y & 255u], g1);
            if (e0 + 2 >= lo && e0 + 2 < hi) atomicAdd(&tacc[v.z & 255u], g2);
            if (e0 + 3 >= lo && e0 + 3 < hi) atomicAdd(&tacc[v.w & 255u], g3);
        }
    }
    __syncthreads();
    if (threadIdx.x < 256) {
        int node = b * 256 + threadIdx.x;
        if (node < N_NODES) {
            float di = dinv[node];
            float a = di * (tacc[threadIdx.x] + xd[node]);   // agg1 (self-loop folded)
            pair[node] = make_float2(a * di, di);
        }
    }
}

// Phase D: s1/s0 accumulate (LDS), finalize + per-graph pool.  4-edge ILP.
__global__ void __launch_bounds__(512)
kD_pass2(const unsigned* __restrict__ binned, const unsigned* __restrict__ bucketBase,
         const float2* __restrict__ pair, const int* __restrict__ batch,
         float* __restrict__ gacc) {
    __shared__ float s1a[256], s0a[256];
    if (threadIdx.x < 256) { s1a[threadIdx.x] = 0.0f; s0a[threadIdx.x] = 0.0f; }
    __syncthreads();
    int b = blockIdx.x;
    unsigned lo = bucketBase[b], hi = bucketBase[b + 1];
    const uint4* b4 = (const uint4*)binned;
    for (unsigned q = lo / 4 + threadIdx.x; q * 4 < hi; q += blockDim.x) {
        uint4 v = b4[q];
        unsigned e0 = q * 4;
        float2 p0 = pair[v.x >> 8];
        float2 p1 = pair[v.y >> 8];
        float2 p2 = pair[v.z >> 8];
        float2 p3 = pair[v.w >> 8];
        if (e0 >= lo && e0 + 3 < hi) {
            atomicAdd(&s1a[v.x & 255u], p0.x); atomicAdd(&s0a[v.x & 255u], p0.y);
            atomicAdd(&s1a[v.y & 255u], p1.x); atomicAdd(&s0a[v.y & 255u], p1.y);
            atomicAdd(&s1a[v.z & 255u], p2.x); atomicAdd(&s0a[v.z & 255u], p2.y);
            atomicAdd(&s1a[v.w & 255u], p3.x); atomicAdd(&s0a[v.w & 255u], p3.y);
        } else {
            if (e0     >= lo && e0     < hi) { atomicAdd(&s1a[v.x & 255u], p0.x); atomicAdd(&s0a[v.x & 255u], p0.y); }
            if (e0 + 1 >= lo && e0 + 1 < hi) { atomicAdd(&s1a[v.y & 255u], p1.x); atomicAdd(&s0a[v.y & 255u], p1.y); }
            if (e0 + 2 >= lo && e0 + 2 < hi) { atomicAdd(&s1a[v.z & 255u], p2.x); atomicAdd(&s0a[v.z & 255u], p2.y); }
            if (e0 + 3 >= lo && e0 + 3 < hi) { atomicAdd(&s1a[v.w & 255u], p3.x); atomicAdd(&s0a[v.w & 255u], p3.y); }
        }
    }
    __syncthreads();
    if (threadIdx.x < 256) {
        int node = b * 256 + threadIdx.x;
        float s1f = 0.0f, s0f = 0.0f;
        int g = 0;
        bool valid = (node < N_NODES);
        if (valid) {
            float2 pr = pair[node];          // {agg1*di, di}
            float di = pr.y;
            s1f = di * (s1a[threadIdx.x] + pr.x);   // self-loop: + agg1*di
            s0f = di * (s0a[threadIdx.x] + di);     // self-loop: + di
            g = batch[node];
        }
        int g0 = __shfl(g, 0);
        bool uni = __all(valid && (g == g0));
        if (uni) {
            for (int off = 32; off; off >>= 1) {
                s1f += __shfl_down(s1f, off);
                s0f += __shfl_down(s0f, off);
            }
            if ((threadIdx.x & 63) == 0) {
                atomicAdd(&gacc[g0], s1f);
                atomicAdd(&gacc[N_GRAPHS + g0], s0f);
                atomicAdd(&gacc[2 * N_GRAPHS + g0], 64.0f);
            }
        } else if (valid) {
            atomicAdd(&gacc[g], s1f);
            atomicAdd(&gacc[N_GRAPHS + g], s0f);
            atomicAdd(&gacc[2 * N_GRAPHS + g], 1.0f);
        }
    }
}

// Final: pooled = (u*GS1 + v*GS0 + cnt*b2)/max(cnt,1); log_softmax over 8 classes
__global__ void k_final(const float* __restrict__ gacc,
                        const float* __restrict__ W1, const float* __restrict__ b1,
                        const float* __restrict__ W2, const float* __restrict__ b2,
                        float* __restrict__ out) {
    int g = threadIdx.x;
    if (g >= N_GRAPHS) return;
    float GS1 = gacc[g];
    float GS0 = gacc[N_GRAPHS + g];
    float cnt = gacc[2 * N_GRAPHS + g];
    float denom = fmaxf(cnt, 1.0f);
    float p[8];
    for (int k = 0; k < 8; ++k) {
        float u = 0.0f, v = 0.0f;
        for (int c = 0; c < 32; ++c) {
            u += W1[c] * W2[c * 8 + k];
            v += b1[c] * W2[c * 8 + k];
        }
        p[k] = (u * GS1 + v * GS0 + cnt * b2[k]) / denom;
    }
    float m = p[0];
    for (int k = 1; k < 8; ++k) m = fmaxf(m, p[k]);
    float s = 0.0f;
    for (int k = 0; k < 8; ++k) s += expf(p[k] - m);
    float l = logf(s);
    for (int k = 0; k < 8; ++k) out[g * 8 + k] = p[k] - m - l;
}

// ============================================================
// Fallback path: global-atomic pipeline (used if ws too small)
// ============================================================

__global__ void k_deg(const int* __restrict__ dst, float* __restrict__ deg) {
    const int4* d4 = (const int4*)dst;
    const int n4 = N_EDGES / 4;
    for (int e = blockIdx.x * blockDim.x + threadIdx.x; e < n4; e += gridDim.x * blockDim.x) {
        int4 d = d4[e];
        atomicAdd(&deg[d.x], 1.0f);
        atomicAdd(&deg[d.y], 1.0f);
        atomicAdd(&deg[d.z], 1.0f);
        atomicAdd(&deg[d.w], 1.0f);
    }
}

__global__ void k_dinv(const float* __restrict__ x, float* __restrict__ deg_dinv,
                       float* __restrict__ xd) {
    int i = blockIdx.x * blockDim.x + threadIdx.x;
    if (i < N_NODES) {
        float dinv = rsqrtf(deg_dinv[i] + 1.0f);
        deg_dinv[i] = dinv;
        xd[i] = x[i] * dinv;
    }
}

__global__ void k_pass1(const int* __restrict__ src, const int* __restrict__ dst,
                        const float* __restrict__ xd, float* __restrict__ t) {
    const int4* s4 = (const int4*)src;
    const int4* d4 = (const int4*)dst;
    const int n4 = N_EDGES / 4;
    for (int e = blockIdx.x * blockDim.x + threadIdx.x; e < n4; e += gridDim.x * blockDim.x) {
        int4 s = s4[e];
        int4 d = d4[e];
        atomicAdd(&t[d.x], xd[s.x]);
        atomicAdd(&t[d.y], xd[s.y]);
        atomicAdd(&t[d.z], xd[s.z]);
        atomicAdd(&t[d.w], xd[s.w]);
    }
}

__global__ void k_agg1(const float* __restrict__ dinv, const float* __restrict__ xd,
                       float* __restrict__ t, float2* __restrict__ pair) {
    int i = blockIdx.x * blockDim.x + threadIdx.x;
    if (i < N_NODES) {
        float di = dinv[i];
        float a = di * (t[i] + xd[i]);
        t[i] = a;
        pair[i] = make_float2(a * di, di);
    }
}

__global__ void k_pass2(const int* __restrict__ src, const int* __restrict__ dst,
                        const float2* __restrict__ pair,
                        float* __restrict__ s1, float* __restrict__ s0) {
    const int4* s4 = (const int4*)src;
    const int4* d4 = (const int4*)dst;
    const int n4 = N_EDGES / 4;
    for (int e = blockIdx.x * blockDim.x + threadIdx.x; e < n4; e += gridDim.x * blockDim.x) {
        int4 s = s4[e];
        int4 d = d4[e];
        float2 p0 = pair[s.x];
        float2 p1 = pair[s.y];
        float2 p2 = pair[s.z];
        float2 p3 = pair[s.w];
        atomicAdd(&s1[d.x], p0.x); atomicAdd(&s0[d.x], p0.y);
        atomicAdd(&s1[d.y], p1.x); atomicAdd(&s0[d.y], p1.y);
        atomicAdd(&s1[d.z], p2.x); atomicAdd(&s0[d.z], p2.y);
        atomicAdd(&s1[d.w], p3.x); atomicAdd(&s0[d.w], p3.y);
    }
}

__global__ void k_node2(const float* __restrict__ dinv, const float* __restrict__ agg1,
                        const float* __restrict__ s1, const float* __restrict__ s0,
                        const int* __restrict__ batch, float* __restrict__ gacc) {
    int i = blockIdx.x * blockDim.x + threadIdx.x;
    float s1f = 0.0f, s0f = 0.0f;
    int g = 0;
    bool valid = (i < N_NODES);
    if (valid) {
        float di = dinv[i];
        s1f = di * (s1[i] + agg1[i] * di);
        s0f = di * (s0[i] + di);
        g = batch[i];
    }
    int g0 = __shfl(g, 0);
    bool uni = __all(valid && (g == g0));
    if (uni) {
        for (int off = 32; off; off >>= 1) {
            s1f += __shfl_down(s1f, off);
            s0f += __shfl_down(s0f, off);
        }
        if ((threadIdx.x & 63) == 0) {
            atomicAdd(&gacc[g0], s1f);
            atomicAdd(&gacc[N_GRAPHS + g0], s0f);
            atomicAdd(&gacc[2 * N_GRAPHS + g0], 64.0f);
        }
    } else if (valid) {
        atomicAdd(&gacc[g], s1f);
        atomicAdd(&gacc[N_GRAPHS + g], s0f);
        atomicAdd(&gacc[2 * N_GRAPHS + g], 1.0f);
    }
}

// ---------------- launch ----------------

extern "C" void kernel_launch(void* const* d_in, const int* in_sizes, int n_in,
                              void* d_out, int out_size, void* d_ws, size_t ws_size,
                              hipStream_t stream) {
    const float* x     = (const float*)d_in[0];
    const int*   edge  = (const int*)d_in[1];   // int64 in ref; harness delivers int32
    const int*   batch = (const int*)d_in[2];
    const float* W1    = (const float*)d_in[3];
    const float* b1    = (const float*)d_in[4];
    const float* W2    = (const float*)d_in[5];
    const float* b2    = (const float*)d_in[6];
    float* out = (float*)d_out;

    const int* src = edge;
    const int* dst = edge + N_EDGES;

    const size_t o_binned = 0;
    const size_t o_cmat   = o_binned + (size_t)N_EDGES;
    const size_t o_colsum = o_cmat + (size_t)EBLK * NBK;
    const size_t o_bbase  = o_colsum + NBK;
    const size_t o_dinv   = o_bbase + NBK + 1;
    const size_t o_xd     = o_dinv + N_NODES;
    size_t o_pair         = o_xd + N_NODES;
    if (o_pair & 1) o_pair++;                    // 8B align for float2
    const size_t o_gacc   = o_pair + 2 * (size_t)N_NODES;
    const size_t need_u32 = o_gacc + 3 * N_GRAPHS;

    unsigned* ws_u = (unsigned*)d_ws;
    float*    ws_f = (float*)d_ws;

    if (ws_size >= need_u32 * 4) {
        // ---------- fast path ----------
        unsigned* binned     = ws_u + o_binned;
        unsigned* countMat   = ws_u + o_cmat;
        unsigned* colsum     = ws_u + o_colsum;
        unsigned* bucketBase = ws_u + o_bbase;
        float*    dinv       = ws_f + o_dinv;
        float*    xd         = ws_f + o_xd;
        float2*   pair       = (float2*)(ws_f + o_pair);
        float*    gacc       = ws_f + o_gacc;

        hipMemsetAsync(gacc, 0, 3 * N_GRAPHS * sizeof(float), stream);

        kA0_hist   <<<EBLK, 256, 0, stream>>>(dst, countMat);
        kScanBlk   <<<(NBK + 3) / 4, 256, 0, stream>>>(countMat, colsum);
        kScanBkt   <<<1, 832, 0, stream>>>(colsum, bucketBase);
        kA1_scatter<<<EBLK, 256, 0, stream>>>(src, dst, countMat, bucketBase, binned);
        kB_deg     <<<NBK, 512, 0, stream>>>(binned, bucketBase, x, dinv, xd);
        kC_pass1   <<<NBK, 512, 0, stream>>>(binned, bucketBase, xd, dinv, pair);
        kD_pass2   <<<NBK, 512, 0, stream>>>(binned, bucketBase, pair, batch, gacc);
        k_final    <<<1, 128, 0, stream>>>(gacc, W1, b1, W2, b2, out);
    } else {
        // ---------- fallback: global-atomic path ----------
        float* dinv = ws_f;
        float* t    = ws_f + 1 * N_NODES;
        float* s1   = ws_f + 2 * N_NODES;
        float* s0   = ws_f + 3 * N_NODES;
        float* xd   = ws_f + 4 * N_NODES;
        float2* pair = (float2*)(ws_f + 5 * N_NODES);
        float* gacc = ws_f + 7 * N_NODES;

        hipMemsetAsync(ws_f, 0, (size_t)4 * N_NODES * sizeof(float), stream);
        hipMemsetAsync(gacc, 0, (size_t)3 * N_GRAPHS * sizeof(float), stream);

        const int EB = 2048, ET = 256;
        const int NB = (N_NODES + 255) / 256, NT = 256;

        k_deg  <<<EB, ET, 0, stream>>>(dst, dinv);
        k_dinv <<<NB, NT, 0, stream>>>(x, dinv, xd);
        k_pass1<<<EB, ET, 0, stream>>>(src, dst, xd, t);
        k_agg1 <<<NB, NT, 0, stream>>>(dinv, xd, t, pair);
        k_pass2<<<EB, ET, 0, stream>>>(src, dst, pair, s1, s0);
        k_node2<<<NB, NT, 0, stream>>>(dinv, t, s1, s0, batch, gacc);
        k_final<<<1, 128, 0, stream>>>(gacc, W1, b1, W2, b2, out);
    }
}